// Round 5
// baseline (322.055 us; speedup 1.0000x reference)
//
#include <hip/hip_runtime.h>
#include <hip/hip_bf16.h>
#include <math.h>

typedef __bf16 bf16x4 __attribute__((ext_vector_type(4)));
typedef __bf16 bf16x8 __attribute__((ext_vector_type(8)));
typedef float  f32x4  __attribute__((ext_vector_type(4)));

#define S_LEN 2048
#define BATCH 4
#define DMODEL 1280
#define NHEAD 16
#define DHEAD 80
#define KDIM 1280

__device__ __forceinline__ f32x4 mfma_bf16(bf16x8 a, bf16x8 b, f32x4 c) {
  return __builtin_amdgcn_mfma_f32_16x16x32_bf16(a, b, c, 0, 0, 0);
}

__device__ __forceinline__ void gload16(const void* g, void* l) {
  __builtin_amdgcn_global_load_lds(
      (const __attribute__((address_space(1))) unsigned int*)g,
      (__attribute__((address_space(3))) unsigned int*)l, 16, 0, 0);
}

// ---------------- fp32 -> bf16 cast (vectorized) ----------------
__global__ void cast_f32_to_bf16(const float* __restrict__ in,
                                 __bf16* __restrict__ out, int n4) {
  int i = blockIdx.x * 256 + threadIdx.x;
  if (i >= n4) return;
  float4 v = reinterpret_cast<const float4*>(in)[i];
  bf16x4 o;
  o[0] = (__bf16)v.x; o[1] = (__bf16)v.y; o[2] = (__bf16)v.z; o[3] = (__bf16)v.w;
  reinterpret_cast<bf16x4*>(out)[i] = o;
}

// ---------------- sin/cos tables [S][40] ----------------
__global__ void build_sincos(const float* __restrict__ rot,
                             float* __restrict__ ctab, float* __restrict__ stab, int n) {
  int i = blockIdx.x * 256 + threadIdx.x;
  if (i >= n) return;
  float v = rot[i];
  ctab[i] = cosf(v);
  stab[i] = sinf(v);
}

// ---------------- zero page ----------------
__global__ void zero_fill(float* __restrict__ p, int n) {
  int i = blockIdx.x * 256 + threadIdx.x;
  if (i < n) p[i] = 0.0f;
}

// ---------------- GEMM: C[N][E] = A[N][1280] * Bw[E][1280]^T + bias ----------------
// Counted-vmcnt raw-barrier pipeline (pattern proven in attn v3) + XCD-chunked swizzle.
// MODE 0: scatter bf16 to q[B,H,S,80], k[B,H,S,80], vT[B,H,80,S] (V sigma-permuted per 32-chunk)
// MODE 1: fp32 out[N][1280]
template <int MODE>
__global__ __launch_bounds__(256) void gemm_bt(
    const __bf16* __restrict__ A, const __bf16* __restrict__ Bw,
    const float* __restrict__ bias, float* __restrict__ outf,
    __bf16* __restrict__ qw, __bf16* __restrict__ kw, __bf16* __restrict__ vtw)
{
  __shared__ __align__(16) char smem[2][2][16384];  // [buf][A/B][128 rows x 128B (BK=64 bf16)]
  const int tid = threadIdx.x;
  const int lane = tid & 63;
  const int w = tid >> 6;
  const int lr = lane & 15, lg = lane >> 4;
  const int rowblk = (w >> 1) * 64, colblk = (w & 1) * 64;
  const int sxz = (lane & 7) << 4;

  // XCD-chunked swizzle: 64 x-tiles in chunks of 8 per XCD; each XCD's A-panel
  // (8 x 128 rows x 2560 B = 2.6 MB) stays L2-resident across all y-panels.
  const int wg = blockIdx.x;
  const int xcd = wg & 7, idx = wg >> 3;
  const int bx = xcd * 8 + (idx & 7);
  const int by = idx >> 3;
  const int r0 = bx * 128;
  const int c0 = by * 128;
  const char* asrc = (const char*)(A + (size_t)r0 * KDIM);
  const char* bsrc = (const char*)(Bw + (size_t)c0 * KDIM);

  f32x4 acc[4][4] = {};

  auto stage = [&](int buf, int kt) {
    const size_t kb = (size_t)kt * 128;  // byte offset into K dim
#pragma unroll
    for (int i = 0; i < 4; ++i) {
      int L = i * 4096 + tid * 16;
      int r = L >> 7;
      int coff = (L & 127) ^ ((r & 7) << 4);  // inverse-swizzled source
      gload16(asrc + (size_t)r * 2560 + kb + coff, &smem[buf][0][L]);
      gload16(bsrc + (size_t)r * 2560 + kb + coff, &smem[buf][1][L]);
    }
  };

  auto compute = [&](int buf) {
#pragma unroll
    for (int kk = 0; kk < 2; ++kk) {
      const int cb = (kk * 64 + lg * 16) ^ sxz;
      bf16x8 af[4], bfr[4];
#pragma unroll
      for (int rf = 0; rf < 4; ++rf)
        af[rf] = *reinterpret_cast<const bf16x8*>(&smem[buf][0][(rowblk + rf * 16 + lr) * 128 + cb]);
#pragma unroll
      for (int cf = 0; cf < 4; ++cf)
        bfr[cf] = *reinterpret_cast<const bf16x8*>(&smem[buf][1][(colblk + cf * 16 + lr) * 128 + cb]);
#pragma unroll
      for (int rf = 0; rf < 4; ++rf)
#pragma unroll
        for (int cf = 0; cf < 4; ++cf)
          acc[rf][cf] = mfma_bf16(af[rf], bfr[cf], acc[rf][cf]);
    }
  };

  // prologue
  stage(0, 0);
  asm volatile("s_waitcnt vmcnt(0)" ::: "memory");
  __builtin_amdgcn_s_barrier();
  __builtin_amdgcn_sched_barrier(0);

  for (int t = 0; t < 20; ++t) {
    const int buf = t & 1;
    if (t < 19) {
      stage(buf ^ 1, t + 1);                           // prefetch stays in flight
      asm volatile("s_waitcnt vmcnt(8)" ::: "memory"); // tile t landed; t+1's 8 flying
    } else {
      asm volatile("s_waitcnt vmcnt(0)" ::: "memory");
    }
    __builtin_amdgcn_sched_barrier(0);
    __builtin_amdgcn_s_barrier();   // tile t visible to all waves
    __builtin_amdgcn_sched_barrier(0);

    compute(buf);

    __builtin_amdgcn_sched_barrier(0);
    __builtin_amdgcn_s_barrier();   // reads done -> next iter may overwrite buf^1
    __builtin_amdgcn_sched_barrier(0);
  }

  float biasr[4];
#pragma unroll
  for (int cf = 0; cf < 4; ++cf) biasr[cf] = bias[c0 + colblk + cf * 16 + lr];

  if (MODE == 1) {
#pragma unroll
    for (int rf = 0; rf < 4; ++rf)
#pragma unroll
      for (int cf = 0; cf < 4; ++cf) {
        const int c = c0 + colblk + cf * 16 + lr;
#pragma unroll
        for (int j = 0; j < 4; ++j) {
          const int r = r0 + rowblk + rf * 16 + lg * 4 + j;
          outf[(size_t)r * DMODEL + c] = acc[rf][cf][j] + biasr[cf];
        }
      }
  } else {
    const int which = c0 / DMODEL;  // block-uniform (128 | 1280)
#pragma unroll
    for (int cf = 0; cf < 4; ++cf) {
      const int c = c0 + colblk + cf * 16 + lr;
      const int ee = c - which * DMODEL;
      const int h = ee / DHEAD;
      const int dh = ee - h * DHEAD;
#pragma unroll
      for (int rf = 0; rf < 4; ++rf)
#pragma unroll
        for (int j = 0; j < 4; ++j) {
          const int r = r0 + rowblk + rf * 16 + lg * 4 + j;
          const int s = r >> 2, b = r & 3;
          const __bf16 bv = (__bf16)(acc[rf][cf][j] + biasr[cf]);
          if (which == 0)
            qw[((size_t)(b * NHEAD + h) * S_LEN + s) * DHEAD + dh] = bv;
          else if (which == 1)
            kw[((size_t)(b * NHEAD + h) * S_LEN + s) * DHEAD + dh] = bv;
          else {
            // sigma-permute within each 32-chunk so contiguous 16B = PV A-fragment
            const int sp = (s & ~31) | ((s & 12) << 1) | ((s & 16) >> 2) | (s & 3);
            vtw[((size_t)(b * NHEAD + h) * DHEAD + dh) * S_LEN + sp] = bv;
          }
        }
    }
  }
}

// ---------------- RoPE in-place on q,k; q additionally pre-scaled by scale*log2e ----------------
__global__ void rope_kernel(__bf16* __restrict__ qw, __bf16* __restrict__ kw,
                            const float* __restrict__ ctab, const float* __restrict__ stab,
                            float qscale)
{
  int idx = blockIdx.x * 256 + threadIdx.x;  // 2*64*2048*10 threads
  const int j = idx % 10;
  int rest = idx / 10;
  const int s = rest & (S_LEN - 1);
  rest >>= 11;
  const int bh = rest & 63;
  const int isk = rest >> 6;
  __bf16* base = (isk ? kw : qw) + ((size_t)bh * S_LEN + s) * DHEAD;
  const float4 c4 = *reinterpret_cast<const float4*>(ctab + s * 40 + j * 4);
  const float4 s4 = *reinterpret_cast<const float4*>(stab + s * 40 + j * 4);
  bf16x4 a = *reinterpret_cast<bf16x4*>(base + j * 4);
  bf16x4 b = *reinterpret_cast<bf16x4*>(base + 40 + j * 4);
  const float m = isk ? 1.0f : qscale;
  const float cc[4] = {c4.x, c4.y, c4.z, c4.w};
  const float ss[4] = {s4.x, s4.y, s4.z, s4.w};
#pragma unroll
  for (int t = 0; t < 4; ++t) {
    float fa = (float)a[t], fb = (float)b[t];
    a[t] = (__bf16)((fa * cc[t] - fb * ss[t]) * m);
    b[t] = (__bf16)((fb * cc[t] + fa * ss[t]) * m);
  }
  *reinterpret_cast<bf16x4*>(base + j * 4) = a;
  *reinterpret_cast<bf16x4*>(base + 40 + j * 4) = b;
}

// ---------------- attention v3 (known-good, reverted verbatim) ----------------
// 256 threads = 4 waves; wave w owns q rows [w*32, w*32+32). kv-tile 64, 32 iters.
// LDS in MFMA-fragment order (slot*1024 + lane*16): conflict-free reads AND
// global_load_lds staging. Swapped QK^T -> lane-local P; PV k-order permuted via
// sigma-permuted V storage (done in gemm epilogue). Double-buffered, counted vmcnt.
__global__ __launch_bounds__(256, 3) void attn_kernel(
    const __bf16* __restrict__ qw, const __bf16* __restrict__ kw,
    const __bf16* __restrict__ vtw, __bf16* __restrict__ ow,
    const float* __restrict__ zp)
{
  __shared__ __align__(1024) char smem[2][24576];  // [buf][K 12KB | V 12KB]

  const int tid = threadIdx.x;
  const int lane = tid & 63;
  const int w = tid >> 6;             // 0..3
  const int lr = lane & 15, lg = lane >> 4;

  // XCD-aware mapping: all 16 q-tiles of one bh on one XCD
  const int wg = blockIdx.x;          // 0..1023
  const int local = wg >> 3;
  const int bh = (wg & 7) * 8 + (local >> 4);
  const int qt = local & 15;

  const char* qbase = (const char*)(qw + ((size_t)bh * S_LEN + qt * 128) * DHEAD);
  const char* kbase = (const char*)(kw + (size_t)bh * S_LEN * DHEAD);
  const char* vbase = (const char*)(vtw + (size_t)bh * DHEAD * S_LEN);
  const char* zpb = (const char*)zp;

  bf16x8 z8;
#pragma unroll
  for (int i = 0; i < 8; ++i) z8[i] = (__bf16)0.0f;

  // Q fragments (B-operand): q = w*32 + m*16 + lr, d-chunks {0..31,32..63,64..79+pad}
  bf16x8 aq[2][3];
#pragma unroll
  for (int m = 0; m < 2; ++m) {
    const char* rp = qbase + (size_t)(w * 32 + m * 16 + lr) * 160;
    aq[m][0] = *reinterpret_cast<const bf16x8*>(rp + lg * 16);
    aq[m][1] = *reinterpret_cast<const bf16x8*>(rp + 64 + lg * 16);
    aq[m][2] = (lg < 2) ? *reinterpret_cast<const bf16x8*>(rp + 128 + lg * 16) : z8;
  }

  // stage one kv-64 tile: 24 slots x 1KB. K slots s=ks*4+n (12), V slots 12+(mf*2+ks2)
  // (mf=5 dummy -> zeropage). Wave w issues slots w*6..w*6+5 (6 gload16/thread).
  auto stage = [&](int buf, int kt) {
#pragma unroll
    for (int i = 0; i < 6; ++i) {
      const int s = w * 6 + i;
      char* dst = &smem[buf][s * 1024];
      const char* src;
      if (s < 12) {
        const int ks = s >> 2, n = s & 3;
        src = (ks == 2 && lg >= 2)
                ? zpb + lane * 16
                : kbase + (size_t)(kt * 64 + n * 16 + lr) * 160 + ks * 64 + lg * 16;
      } else {
        const int v = s - 12;
        const int mf = v >> 1, ks2 = v & 1;
        src = (mf == 5)
                ? zpb + lane * 16
                : vbase + (size_t)(mf * 16 + lr) * 4096 + (size_t)(kt * 64 + ks2 * 32 + lg * 8) * 2;
      }
      gload16(src, dst);
    }
  };

  f32x4 accO[5][2] = {};  // O[dh = mf*16+lg*4+j][q = w*32 + m*16 + lr]
  f32x4 denp[2] = {};

  stage(0, 0);
  asm volatile("s_waitcnt vmcnt(0)" ::: "memory");
  __builtin_amdgcn_s_barrier();
  __builtin_amdgcn_sched_barrier(0);

  for (int t = 0; t < 32; ++t) {
    const int buf = t & 1;
    if (t < 31) {
      stage(buf ^ 1, t + 1);                          // prefetch stays in flight
      asm volatile("s_waitcnt vmcnt(6)" ::: "memory"); // tile t landed; t+1 flying
    } else {
      asm volatile("s_waitcnt vmcnt(0)" ::: "memory");
    }
    __builtin_amdgcn_sched_barrier(0);
    __builtin_amdgcn_s_barrier();   // tile t visible to all waves
    __builtin_amdgcn_sched_barrier(0);

    const char* Kb = smem[buf];
    const char* Vb = smem[buf] + 12288;

    // S^T = K * Q^T  (Q pre-scaled by scale*log2e, so p = exp2(s))
    f32x4 sc[2][4] = {};
#pragma unroll
    for (int n = 0; n < 4; ++n) {
      bf16x8 af0 = *reinterpret_cast<const bf16x8*>(Kb + (0 * 4 + n) * 1024 + lane * 16);
      bf16x8 af1 = *reinterpret_cast<const bf16x8*>(Kb + (1 * 4 + n) * 1024 + lane * 16);
      bf16x8 af2 = *reinterpret_cast<const bf16x8*>(Kb + (2 * 4 + n) * 1024 + lane * 16);
#pragma unroll
      for (int m = 0; m < 2; ++m) {
        sc[m][n] = mfma_bf16(af0, aq[m][0], sc[m][n]);
        sc[m][n] = mfma_bf16(af1, aq[m][1], sc[m][n]);
        sc[m][n] = mfma_bf16(af2, aq[m][2], sc[m][n]);
      }
    }

    // p = exp2(s); den partials; lane-local P pack (permuted k-order)
    bf16x8 bp[2][2];
#pragma unroll
    for (int m = 0; m < 2; ++m)
#pragma unroll
      for (int n = 0; n < 4; ++n) {
        f32x4 p;
#pragma unroll
        for (int j = 0; j < 4; ++j) p[j] = exp2f(sc[m][n][j]);
        denp[m] += p;
#pragma unroll
        for (int j = 0; j < 4; ++j) bp[m][n >> 1][(n & 1) * 4 + j] = (__bf16)p[j];
      }

    // O += P*V (V pre-permuted in global so fragments are contiguous)
#pragma unroll
    for (int ks2 = 0; ks2 < 2; ++ks2)
#pragma unroll
      for (int mf = 0; mf < 5; ++mf) {
        bf16x8 av = *reinterpret_cast<const bf16x8*>(Vb + (mf * 2 + ks2) * 1024 + lane * 16);
        accO[mf][0] = mfma_bf16(av, bp[0][ks2], accO[mf][0]);
        accO[mf][1] = mfma_bf16(av, bp[1][ks2], accO[mf][1]);
      }

    __builtin_amdgcn_sched_barrier(0);
    __builtin_amdgcn_s_barrier();   // reads done -> next iter may overwrite buf^1
    __builtin_amdgcn_sched_barrier(0);
  }

  __syncthreads();

  // den: in-lane 4 + butterfly across lg (q = w*32 + m*16 + lr)
  float rinv[2];
#pragma unroll
  for (int m = 0; m < 2; ++m) {
    float v = denp[m][0] + denp[m][1] + denp[m][2] + denp[m][3];
    v += __shfl_xor(v, 16);
    v += __shfl_xor(v, 32);
    rinv[m] = 1.0f / v;
  }

  // O -> LDS (reuse smem), then coalesced global write
  char* sOut = smem[0];
#pragma unroll
  for (int mf = 0; mf < 5; ++mf)
#pragma unroll
    for (int m = 0; m < 2; ++m) {
      bf16x4 o4;
#pragma unroll
      for (int j = 0; j < 4; ++j) o4[j] = (__bf16)(accO[mf][m][j] * rinv[m]);
      *reinterpret_cast<bf16x4*>(sOut + (size_t)(w * 32 + m * 16 + lr) * 160 + (mf * 16 + lg * 4) * 2) = o4;
    }
  __syncthreads();

  const int b = bh >> 4, h = bh & 15;
#pragma unroll
  for (int i = 0; i < 5; ++i) {
    int c = i * 256 + tid;
    int row = c / 10, slot = c - row * 10;
    int token = (qt * 128 + row) * 4 + b;
    *reinterpret_cast<bf16x8*>((char*)ow + (size_t)token * 2560 + h * 160 + slot * 16) =
        *reinterpret_cast<const bf16x8*>(sOut + row * 160 + slot * 16);
  }
}

// ---------------- launcher ----------------
extern "C" void kernel_launch(void* const* d_in, const int* in_sizes, int n_in,
                              void* d_out, int out_size, void* d_ws, size_t ws_size,
                              hipStream_t stream)
{
  const float* hidden = (const float*)d_in[0];
  const float* rot    = (const float*)d_in[1];
  const float* w1     = (const float*)d_in[2];
  const float* b1     = (const float*)d_in[3];
  const float* w2     = (const float*)d_in[4];
  const float* b2     = (const float*)d_in[5];
  float* out = (float*)d_out;

  char* ws = (char*)d_ws;
  __bf16* Xbf  = (__bf16*)(ws);                 // 8192x1280 bf16      = 20,971,520 B
  __bf16* W1bf = (__bf16*)(ws + 20971520);      // 3840x1280 bf16      =  9,830,400 B
  __bf16* W2bf = (__bf16*)(ws + 30801920);      // 1280x1280 bf16      =  3,276,800 B
  float*  ctab = (float*)(ws + 34078720);       // 2048x40 f32         =    327,680 B
  float*  stab = (float*)(ws + 34406400);       //                     =    327,680 B
  __bf16* qwp  = (__bf16*)(ws + 34734080);      // [B,H,S,80] bf16     = 20,971,520 B
  __bf16* kwp  = (__bf16*)(ws + 55705600);      // [B,H,S,80] bf16     = 20,971,520 B
  __bf16* vtwp = (__bf16*)(ws + 76677120);      // [B,H,80,S] bf16 (sigma-permuted) = 20,971,520 B
  __bf16* owp  = (__bf16*)(ws + 97648640);      // [S*B,1280] bf16     = 20,971,520 B
  float*  zp   = (float*)(ws + 118620160);      // 4KB zero page

  cast_f32_to_bf16<<<10240, 256, 0, stream>>>(hidden, Xbf, 2621440);
  cast_f32_to_bf16<<<4800, 256, 0, stream>>>(w1, W1bf, 1228800);
  cast_f32_to_bf16<<<1600, 256, 0, stream>>>(w2, W2bf, 409600);
  build_sincos<<<320, 256, 0, stream>>>(rot, ctab, stab, 81920);
  zero_fill<<<4, 256, 0, stream>>>(zp, 1024);

  gemm_bt<0><<<1920, 256, 0, stream>>>(Xbf, W1bf, b1, nullptr, qwp, kwp, vtwp);

  const float qscale = 1.4426950408889634f / sqrtf(80.0f);  // scale * log2(e), folded into Q
  rope_kernel<<<10240, 256, 0, stream>>>(qwp, kwp, ctab, stab, qscale);

  attn_kernel<<<1024, 256, 0, stream>>>(qwp, kwp, vtwp, owp, zp);

  gemm_bt<1><<<640, 256, 0, stream>>>(owp, W2bf, b2, out, nullptr, nullptr, nullptr);
}

// Round 6
// 309.782 us; speedup vs baseline: 1.0396x; 1.0396x over previous
//
#include <hip/hip_runtime.h>
#include <hip/hip_bf16.h>
#include <math.h>

typedef __bf16 bf16x4 __attribute__((ext_vector_type(4)));
typedef __bf16 bf16x8 __attribute__((ext_vector_type(8)));
typedef float  f32x4  __attribute__((ext_vector_type(4)));

#define S_LEN 2048
#define BATCH 4
#define DMODEL 1280
#define NHEAD 16
#define DHEAD 80
#define KDIM 1280

__device__ __forceinline__ f32x4 mfma_bf16(bf16x8 a, bf16x8 b, f32x4 c) {
  return __builtin_amdgcn_mfma_f32_16x16x32_bf16(a, b, c, 0, 0, 0);
}

__device__ __forceinline__ void gload16(const void* g, void* l) {
  __builtin_amdgcn_global_load_lds(
      (const __attribute__((address_space(1))) unsigned int*)g,
      (__attribute__((address_space(3))) unsigned int*)l, 16, 0, 0);
}

// ---------------- fp32 -> bf16 cast (vectorized) ----------------
__global__ void cast_f32_to_bf16(const float* __restrict__ in,
                                 __bf16* __restrict__ out, int n4) {
  int i = blockIdx.x * 256 + threadIdx.x;
  if (i >= n4) return;
  float4 v = reinterpret_cast<const float4*>(in)[i];
  bf16x4 o;
  o[0] = (__bf16)v.x; o[1] = (__bf16)v.y; o[2] = (__bf16)v.z; o[3] = (__bf16)v.w;
  reinterpret_cast<bf16x4*>(out)[i] = o;
}

// ---------------- sin/cos tables [S][40] ----------------
__global__ void build_sincos(const float* __restrict__ rot,
                             float* __restrict__ ctab, float* __restrict__ stab, int n) {
  int i = blockIdx.x * 256 + threadIdx.x;
  if (i >= n) return;
  float v = rot[i];
  ctab[i] = cosf(v);
  stab[i] = sinf(v);
}

// ---------------- zero page ----------------
__global__ void zero_fill(float* __restrict__ p, int n) {
  int i = blockIdx.x * 256 + threadIdx.x;
  if (i < n) p[i] = 0.0f;
}

// ---------------- QKV GEMM, 256x256 tile, BK=64, 8 waves ----------------
// C[N8192][E3840] = A[r][1280] * Bw[e][1280]^T + bias, scattered to
// q[B,H,S,80], k[B,H,S,80], vT[B,H,80,S] (V sigma-permuted per 32-chunk).
// WAR-safe by capacity: slot (n+1)&1 holds K-tile n-1 whose readers finished
// before K-tile n began; single vmcnt(0)+barrier per K-tile, drain issued a
// full compute phase after the stage.
__global__ __launch_bounds__(512, 2) void gemm256_qkv(
    const __bf16* __restrict__ A, const __bf16* __restrict__ Bw,
    const float* __restrict__ bias,
    __bf16* __restrict__ qw, __bf16* __restrict__ kw, __bf16* __restrict__ vtw)
{
  __shared__ __align__(1024) char smem[2][65536];  // [slot][A 32KB | B 32KB]
  const int tid = threadIdx.x;
  const int lane = tid & 63;
  const int w = tid >> 6;             // 0..7
  const int lr = lane & 15, lg = lane >> 4;
  const int wr = w >> 2, wc = w & 3;  // wave owns C rows wr*128..+128, cols wc*64..+64

  // XCD-chunked swizzle: 4 bx-panels per XCD (A panel 2.6 MB, L2-resident)
  const int wg = blockIdx.x;          // 0..479
  const int xcd = wg & 7, idx = wg >> 3;  // idx 0..59
  const int bx = xcd * 4 + (idx & 3);
  const int by = idx >> 2;
  const int r0 = bx * 256, c0 = by * 256;
  const char* asrc = (const char*)(A + (size_t)r0 * KDIM);
  const char* bsrc = (const char*)(Bw + (size_t)c0 * KDIM);

  f32x4 acc[8][4] = {};

  auto stage = [&](int buf, int kt) {
    const size_t kb = (size_t)kt * 128;  // byte offset into K dim
#pragma unroll
    for (int i = 0; i < 8; ++i) {
      const int L = i * 8192 + tid * 16;       // 0..65535 linear dest
      const int r = (L & 32767) >> 7;          // row within A or B panel
      const int coff = (L & 127) ^ ((r & 7) << 4);  // inverse-swizzled source
      const char* s = (i < 4 ? asrc : bsrc) + (size_t)r * 2560 + kb + coff;
      gload16(s, &smem[buf][L]);
    }
  };

  auto compute = [&](int buf) {
#pragma unroll
    for (int kk = 0; kk < 2; ++kk) {
      bf16x8 af[8], bfr[4];
#pragma unroll
      for (int rt = 0; rt < 8; ++rt) {
        const int row = wr * 128 + rt * 16 + lr;
        af[rt] = *reinterpret_cast<const bf16x8*>(
            &smem[buf][row * 128 + ((kk * 64 + lg * 16) ^ ((row & 7) << 4))]);
      }
#pragma unroll
      for (int ct = 0; ct < 4; ++ct) {
        const int row = wc * 64 + ct * 16 + lr;
        bfr[ct] = *reinterpret_cast<const bf16x8*>(
            &smem[buf][32768 + row * 128 + ((kk * 64 + lg * 16) ^ ((row & 7) << 4))]);
      }
#pragma unroll
      for (int rt = 0; rt < 8; ++rt)
#pragma unroll
        for (int ct = 0; ct < 4; ++ct)
          acc[rt][ct] = mfma_bf16(af[rt], bfr[ct], acc[rt][ct]);
    }
  };

  // prologue
  stage(0, 0);
  asm volatile("s_waitcnt vmcnt(0)" ::: "memory");
  __builtin_amdgcn_s_barrier();
  __builtin_amdgcn_sched_barrier(0);

  for (int t = 0; t < 20; ++t) {
    const int buf = t & 1;
    if (t < 19) stage(buf ^ 1, t + 1);  // writes slot holding K-tile t-1 (readers done)
    compute(buf);
    __builtin_amdgcn_sched_barrier(0);
    asm volatile("s_waitcnt vmcnt(0)" ::: "memory");  // t+1 landed (issued ~1 phase ago)
    __builtin_amdgcn_sched_barrier(0);
    __builtin_amdgcn_s_barrier();
    __builtin_amdgcn_sched_barrier(0);
  }

  // epilogue: scatter
  const int which = c0 / DMODEL;  // block-uniform (1280 = 5 x 256)
  float biasr[4];
#pragma unroll
  for (int ct = 0; ct < 4; ++ct) biasr[ct] = bias[c0 + wc * 64 + ct * 16 + lr];

#pragma unroll
  for (int ct = 0; ct < 4; ++ct) {
    const int c = c0 + wc * 64 + ct * 16 + lr;
    const int ee = c - which * DMODEL;
    const int h = ee / DHEAD;
    const int dh = ee - h * DHEAD;
#pragma unroll
    for (int rt = 0; rt < 8; ++rt)
#pragma unroll
      for (int j = 0; j < 4; ++j) {
        const int r = r0 + wr * 128 + rt * 16 + lg * 4 + j;
        const int s = r >> 2, b = r & 3;
        const __bf16 bv = (__bf16)(acc[rt][ct][j] + biasr[ct]);
        if (which == 0)
          qw[((size_t)(b * NHEAD + h) * S_LEN + s) * DHEAD + dh] = bv;
        else if (which == 1)
          kw[((size_t)(b * NHEAD + h) * S_LEN + s) * DHEAD + dh] = bv;
        else {
          // sigma-permute within each 32-chunk so contiguous 16B = PV A-fragment
          const int sp = (s & ~31) | ((s & 12) << 1) | ((s & 16) >> 2) | (s & 3);
          vtw[((size_t)(b * NHEAD + h) * DHEAD + dh) * S_LEN + sp] = bv;
        }
      }
  }
}

// ---------------- out-proj GEMM (128x128, proven): C = A * Bw^T + bias, fp32 out ----------------
template <int MODE>
__global__ __launch_bounds__(256) void gemm_bt(
    const __bf16* __restrict__ A, const __bf16* __restrict__ Bw,
    const float* __restrict__ bias, float* __restrict__ outf)
{
  __shared__ __align__(16) char smem[2][2][16384];  // [buf][A/B][128 rows x 128B (BK=64 bf16)]
  const int tid = threadIdx.x;
  const int lane = tid & 63;
  const int w = tid >> 6;
  const int lr = lane & 15, lg = lane >> 4;
  const int rowblk = (w >> 1) * 64, colblk = (w & 1) * 64;
  const int sxz = (lane & 7) << 4;

  const int wg = blockIdx.x;
  const int xcd = wg & 7, idx = wg >> 3;
  const int bx = xcd * 8 + (idx & 7);
  const int by = idx >> 3;
  const int r0 = bx * 128;
  const int c0 = by * 128;
  const char* asrc = (const char*)(A + (size_t)r0 * KDIM);
  const char* bsrc = (const char*)(Bw + (size_t)c0 * KDIM);

  f32x4 acc[4][4] = {};

  auto stage = [&](int buf, int kt) {
    const size_t kb = (size_t)kt * 128;  // byte offset into K dim
#pragma unroll
    for (int i = 0; i < 4; ++i) {
      int L = i * 4096 + tid * 16;
      int r = L >> 7;
      int coff = (L & 127) ^ ((r & 7) << 4);  // inverse-swizzled source
      gload16(asrc + (size_t)r * 2560 + kb + coff, &smem[buf][0][L]);
      gload16(bsrc + (size_t)r * 2560 + kb + coff, &smem[buf][1][L]);
    }
  };

  auto compute = [&](int buf) {
#pragma unroll
    for (int kk = 0; kk < 2; ++kk) {
      const int cb = (kk * 64 + lg * 16) ^ sxz;
      bf16x8 af[4], bfr[4];
#pragma unroll
      for (int rf = 0; rf < 4; ++rf)
        af[rf] = *reinterpret_cast<const bf16x8*>(&smem[buf][0][(rowblk + rf * 16 + lr) * 128 + cb]);
#pragma unroll
      for (int cf = 0; cf < 4; ++cf)
        bfr[cf] = *reinterpret_cast<const bf16x8*>(&smem[buf][1][(colblk + cf * 16 + lr) * 128 + cb]);
#pragma unroll
      for (int rf = 0; rf < 4; ++rf)
#pragma unroll
        for (int cf = 0; cf < 4; ++cf)
          acc[rf][cf] = mfma_bf16(af[rf], bfr[cf], acc[rf][cf]);
    }
  };

  stage(0, 0);
  asm volatile("s_waitcnt vmcnt(0)" ::: "memory");
  __builtin_amdgcn_s_barrier();
  __builtin_amdgcn_sched_barrier(0);

  for (int t = 0; t < 20; ++t) {
    const int buf = t & 1;
    if (t < 19) {
      stage(buf ^ 1, t + 1);
      asm volatile("s_waitcnt vmcnt(8)" ::: "memory");
    } else {
      asm volatile("s_waitcnt vmcnt(0)" ::: "memory");
    }
    __builtin_amdgcn_sched_barrier(0);
    __builtin_amdgcn_s_barrier();
    __builtin_amdgcn_sched_barrier(0);

    compute(buf);

    __builtin_amdgcn_sched_barrier(0);
    __builtin_amdgcn_s_barrier();
    __builtin_amdgcn_sched_barrier(0);
  }

  float biasr[4];
#pragma unroll
  for (int cf = 0; cf < 4; ++cf) biasr[cf] = bias[c0 + colblk + cf * 16 + lr];

#pragma unroll
  for (int rf = 0; rf < 4; ++rf)
#pragma unroll
    for (int cf = 0; cf < 4; ++cf) {
      const int c = c0 + colblk + cf * 16 + lr;
#pragma unroll
      for (int j = 0; j < 4; ++j) {
        const int r = r0 + rowblk + rf * 16 + lg * 4 + j;
        outf[(size_t)r * DMODEL + c] = acc[rf][cf][j] + biasr[cf];
      }
    }
}

// ---------------- RoPE in-place on q,k; q additionally pre-scaled by scale*log2e ----------------
__global__ void rope_kernel(__bf16* __restrict__ qw, __bf16* __restrict__ kw,
                            const float* __restrict__ ctab, const float* __restrict__ stab,
                            float qscale)
{
  int idx = blockIdx.x * 256 + threadIdx.x;  // 2*64*2048*10 threads
  const int j = idx % 10;
  int rest = idx / 10;
  const int s = rest & (S_LEN - 1);
  rest >>= 11;
  const int bh = rest & 63;
  const int isk = rest >> 6;
  __bf16* base = (isk ? kw : qw) + ((size_t)bh * S_LEN + s) * DHEAD;
  const float4 c4 = *reinterpret_cast<const float4*>(ctab + s * 40 + j * 4);
  const float4 s4 = *reinterpret_cast<const float4*>(stab + s * 40 + j * 4);
  bf16x4 a = *reinterpret_cast<bf16x4*>(base + j * 4);
  bf16x4 b = *reinterpret_cast<bf16x4*>(base + 40 + j * 4);
  const float m = isk ? 1.0f : qscale;
  const float cc[4] = {c4.x, c4.y, c4.z, c4.w};
  const float ss[4] = {s4.x, s4.y, s4.z, s4.w};
#pragma unroll
  for (int t = 0; t < 4; ++t) {
    float fa = (float)a[t], fb = (float)b[t];
    a[t] = (__bf16)((fa * cc[t] - fb * ss[t]) * m);
    b[t] = (__bf16)((fb * cc[t] + fa * ss[t]) * m);
  }
  *reinterpret_cast<bf16x4*>(base + j * 4) = a;
  *reinterpret_cast<bf16x4*>(base + 40 + j * 4) = b;
}

// ---------------- attention v3 (known-good, unchanged) ----------------
__global__ __launch_bounds__(256, 3) void attn_kernel(
    const __bf16* __restrict__ qw, const __bf16* __restrict__ kw,
    const __bf16* __restrict__ vtw, __bf16* __restrict__ ow,
    const float* __restrict__ zp)
{
  __shared__ __align__(1024) char smem[2][24576];  // [buf][K 12KB | V 12KB]

  const int tid = threadIdx.x;
  const int lane = tid & 63;
  const int w = tid >> 6;             // 0..3
  const int lr = lane & 15, lg = lane >> 4;

  // XCD-aware mapping: all 16 q-tiles of one bh on one XCD
  const int wg = blockIdx.x;          // 0..1023
  const int local = wg >> 3;
  const int bh = (wg & 7) * 8 + (local >> 4);
  const int qt = local & 15;

  const char* qbase = (const char*)(qw + ((size_t)bh * S_LEN + qt * 128) * DHEAD);
  const char* kbase = (const char*)(kw + (size_t)bh * S_LEN * DHEAD);
  const char* vbase = (const char*)(vtw + (size_t)bh * DHEAD * S_LEN);
  const char* zpb = (const char*)zp;

  bf16x8 z8;
#pragma unroll
  for (int i = 0; i < 8; ++i) z8[i] = (__bf16)0.0f;

  // Q fragments (B-operand): q = w*32 + m*16 + lr, d-chunks {0..31,32..63,64..79+pad}
  bf16x8 aq[2][3];
#pragma unroll
  for (int m = 0; m < 2; ++m) {
    const char* rp = qbase + (size_t)(w * 32 + m * 16 + lr) * 160;
    aq[m][0] = *reinterpret_cast<const bf16x8*>(rp + lg * 16);
    aq[m][1] = *reinterpret_cast<const bf16x8*>(rp + 64 + lg * 16);
    aq[m][2] = (lg < 2) ? *reinterpret_cast<const bf16x8*>(rp + 128 + lg * 16) : z8;
  }

  // stage one kv-64 tile: 24 slots x 1KB. K slots s=ks*4+n (12), V slots 12+(mf*2+ks2)
  // (mf=5 dummy -> zeropage). Wave w issues slots w*6..w*6+5 (6 gload16/thread).
  auto stage = [&](int buf, int kt) {
#pragma unroll
    for (int i = 0; i < 6; ++i) {
      const int s = w * 6 + i;
      char* dst = &smem[buf][s * 1024];
      const char* src;
      if (s < 12) {
        const int ks = s >> 2, n = s & 3;
        src = (ks == 2 && lg >= 2)
                ? zpb + lane * 16
                : kbase + (size_t)(kt * 64 + n * 16 + lr) * 160 + ks * 64 + lg * 16;
      } else {
        const int v = s - 12;
        const int mf = v >> 1, ks2 = v & 1;
        src = (mf == 5)
                ? zpb + lane * 16
                : vbase + (size_t)(mf * 16 + lr) * 4096 + (size_t)(kt * 64 + ks2 * 32 + lg * 8) * 2;
      }
      gload16(src, dst);
    }
  };

  f32x4 accO[5][2] = {};  // O[dh = mf*16+lg*4+j][q = w*32 + m*16 + lr]
  f32x4 denp[2] = {};

  stage(0, 0);
  asm volatile("s_waitcnt vmcnt(0)" ::: "memory");
  __builtin_amdgcn_s_barrier();
  __builtin_amdgcn_sched_barrier(0);

  for (int t = 0; t < 32; ++t) {
    const int buf = t & 1;
    if (t < 31) {
      stage(buf ^ 1, t + 1);                          // prefetch stays in flight
      asm volatile("s_waitcnt vmcnt(6)" ::: "memory"); // tile t landed; t+1 flying
    } else {
      asm volatile("s_waitcnt vmcnt(0)" ::: "memory");
    }
    __builtin_amdgcn_sched_barrier(0);
    __builtin_amdgcn_s_barrier();   // tile t visible to all waves
    __builtin_amdgcn_sched_barrier(0);

    const char* Kb = smem[buf];
    const char* Vb = smem[buf] + 12288;

    // S^T = K * Q^T  (Q pre-scaled by scale*log2e, so p = exp2(s))
    f32x4 sc[2][4] = {};
#pragma unroll
    for (int n = 0; n < 4; ++n) {
      bf16x8 af0 = *reinterpret_cast<const bf16x8*>(Kb + (0 * 4 + n) * 1024 + lane * 16);
      bf16x8 af1 = *reinterpret_cast<const bf16x8*>(Kb + (1 * 4 + n) * 1024 + lane * 16);
      bf16x8 af2 = *reinterpret_cast<const bf16x8*>(Kb + (2 * 4 + n) * 1024 + lane * 16);
#pragma unroll
      for (int m = 0; m < 2; ++m) {
        sc[m][n] = mfma_bf16(af0, aq[m][0], sc[m][n]);
        sc[m][n] = mfma_bf16(af1, aq[m][1], sc[m][n]);
        sc[m][n] = mfma_bf16(af2, aq[m][2], sc[m][n]);
      }
    }

    // p = exp2(s); den partials; lane-local P pack (permuted k-order)
    bf16x8 bp[2][2];
#pragma unroll
    for (int m = 0; m < 2; ++m)
#pragma unroll
      for (int n = 0; n < 4; ++n) {
        f32x4 p;
#pragma unroll
        for (int j = 0; j < 4; ++j) p[j] = exp2f(sc[m][n][j]);
        denp[m] += p;
#pragma unroll
        for (int j = 0; j < 4; ++j) bp[m][n >> 1][(n & 1) * 4 + j] = (__bf16)p[j];
      }

    // O += P*V (V pre-permuted in global so fragments are contiguous)
#pragma unroll
    for (int ks2 = 0; ks2 < 2; ++ks2)
#pragma unroll
      for (int mf = 0; mf < 5; ++mf) {
        bf16x8 av = *reinterpret_cast<const bf16x8*>(Vb + (mf * 2 + ks2) * 1024 + lane * 16);
        accO[mf][0] = mfma_bf16(av, bp[0][ks2], accO[mf][0]);
        accO[mf][1] = mfma_bf16(av, bp[1][ks2], accO[mf][1]);
      }

    __builtin_amdgcn_sched_barrier(0);
    __builtin_amdgcn_s_barrier();   // reads done -> next iter may overwrite buf^1
    __builtin_amdgcn_sched_barrier(0);
  }

  __syncthreads();

  // den: in-lane 4 + butterfly across lg (q = w*32 + m*16 + lr)
  float rinv[2];
#pragma unroll
  for (int m = 0; m < 2; ++m) {
    float v = denp[m][0] + denp[m][1] + denp[m][2] + denp[m][3];
    v += __shfl_xor(v, 16);
    v += __shfl_xor(v, 32);
    rinv[m] = 1.0f / v;
  }

  // O -> LDS (reuse smem), then coalesced global write
  char* sOut = smem[0];
#pragma unroll
  for (int mf = 0; mf < 5; ++mf)
#pragma unroll
    for (int m = 0; m < 2; ++m) {
      bf16x4 o4;
#pragma unroll
      for (int j = 0; j < 4; ++j) o4[j] = (__bf16)(accO[mf][m][j] * rinv[m]);
      *reinterpret_cast<bf16x4*>(sOut + (size_t)(w * 32 + m * 16 + lr) * 160 + (mf * 16 + lg * 4) * 2) = o4;
    }
  __syncthreads();

  const int b = bh >> 4, h = bh & 15;
#pragma unroll
  for (int i = 0; i < 5; ++i) {
    int c = i * 256 + tid;
    int row = c / 10, slot = c - row * 10;
    int token = (qt * 128 + row) * 4 + b;
    *reinterpret_cast<bf16x8*>((char*)ow + (size_t)token * 2560 + h * 160 + slot * 16) =
        *reinterpret_cast<const bf16x8*>(sOut + row * 160 + slot * 16);
  }
}

// ---------------- launcher ----------------
extern "C" void kernel_launch(void* const* d_in, const int* in_sizes, int n_in,
                              void* d_out, int out_size, void* d_ws, size_t ws_size,
                              hipStream_t stream)
{
  const float* hidden = (const float*)d_in[0];
  const float* rot    = (const float*)d_in[1];
  const float* w1     = (const float*)d_in[2];
  const float* b1     = (const float*)d_in[3];
  const float* w2     = (const float*)d_in[4];
  const float* b2     = (const float*)d_in[5];
  float* out = (float*)d_out;

  char* ws = (char*)d_ws;
  __bf16* Xbf  = (__bf16*)(ws);                 // 8192x1280 bf16      = 20,971,520 B
  __bf16* W1bf = (__bf16*)(ws + 20971520);      // 3840x1280 bf16      =  9,830,400 B
  __bf16* W2bf = (__bf16*)(ws + 30801920);      // 1280x1280 bf16      =  3,276,800 B
  float*  ctab = (float*)(ws + 34078720);       // 2048x40 f32         =    327,680 B
  float*  stab = (float*)(ws + 34406400);       //                     =    327,680 B
  __bf16* qwp  = (__bf16*)(ws + 34734080);      // [B,H,S,80] bf16     = 20,971,520 B
  __bf16* kwp  = (__bf16*)(ws + 55705600);      // [B,H,S,80] bf16     = 20,971,520 B
  __bf16* vtwp = (__bf16*)(ws + 76677120);      // [B,H,80,S] bf16 (sigma-permuted) = 20,971,520 B
  __bf16* owp  = (__bf16*)(ws + 97648640);      // [S*B,1280] bf16     = 20,971,520 B
  float*  zp   = (float*)(ws + 118620160);      // 4KB zero page

  cast_f32_to_bf16<<<10240, 256, 0, stream>>>(hidden, Xbf, 2621440);
  cast_f32_to_bf16<<<4800, 256, 0, stream>>>(w1, W1bf, 1228800);
  cast_f32_to_bf16<<<1600, 256, 0, stream>>>(w2, W2bf, 409600);
  build_sincos<<<320, 256, 0, stream>>>(rot, ctab, stab, 81920);
  zero_fill<<<4, 256, 0, stream>>>(zp, 1024);

  gemm256_qkv<<<480, 512, 0, stream>>>(Xbf, W1bf, b1, qwp, kwp, vtwp);

  const float qscale = 1.4426950408889634f / sqrtf(80.0f);  // scale * log2(e), folded into Q
  rope_kernel<<<10240, 256, 0, stream>>>(qwp, kwp, ctab, stab, qscale);

  attn_kernel<<<1024, 256, 0, stream>>>(qwp, kwp, vtwp, owp, zp);

  gemm_bt<1><<<640, 256, 0, stream>>>(owp, W2bf, b2, out);
}

// Round 7
// 276.325 us; speedup vs baseline: 1.1655x; 1.1211x over previous
//
#include <hip/hip_runtime.h>
#include <hip/hip_bf16.h>
#include <math.h>

typedef __bf16 bf16x4 __attribute__((ext_vector_type(4)));
typedef __bf16 bf16x8 __attribute__((ext_vector_type(8)));
typedef float  f32x4  __attribute__((ext_vector_type(4)));

#define S_LEN 2048
#define BATCH 4
#define DMODEL 1280
#define NHEAD 16
#define DHEAD 80
#define KDIM 1280

__device__ __forceinline__ f32x4 mfma_bf16(bf16x8 a, bf16x8 b, f32x4 c) {
  return __builtin_amdgcn_mfma_f32_16x16x32_bf16(a, b, c, 0, 0, 0);
}

__device__ __forceinline__ void gload16(const void* g, void* l) {
  __builtin_amdgcn_global_load_lds(
      (const __attribute__((address_space(1))) unsigned int*)g,
      (__attribute__((address_space(3))) unsigned int*)l, 16, 0, 0);
}

// ---------------- fp32 -> bf16 cast (vectorized) ----------------
__global__ void cast_f32_to_bf16(const float* __restrict__ in,
                                 __bf16* __restrict__ out, int n4) {
  int i = blockIdx.x * 256 + threadIdx.x;
  if (i >= n4) return;
  float4 v = reinterpret_cast<const float4*>(in)[i];
  bf16x4 o;
  o[0] = (__bf16)v.x; o[1] = (__bf16)v.y; o[2] = (__bf16)v.z; o[3] = (__bf16)v.w;
  reinterpret_cast<bf16x4*>(out)[i] = o;
}

// ---------------- sin/cos tables [S][40] ----------------
__global__ void build_sincos(const float* __restrict__ rot,
                             float* __restrict__ ctab, float* __restrict__ stab, int n) {
  int i = blockIdx.x * 256 + threadIdx.x;
  if (i >= n) return;
  float v = rot[i];
  ctab[i] = cosf(v);
  stab[i] = sinf(v);
}

// ---------------- zero page ----------------
__global__ void zero_fill(float* __restrict__ p, int n) {
  int i = blockIdx.x * 256 + threadIdx.x;
  if (i < n) p[i] = 0.0f;
}

// ---------------- QKV GEMM, 256x256 tile, BK=64, 8 waves (unchanged from R6) ----------------
__global__ __launch_bounds__(512, 2) void gemm256_qkv(
    const __bf16* __restrict__ A, const __bf16* __restrict__ Bw,
    const float* __restrict__ bias,
    __bf16* __restrict__ qw, __bf16* __restrict__ kw, __bf16* __restrict__ vtw)
{
  __shared__ __align__(1024) char smem[2][65536];  // [slot][A 32KB | B 32KB]
  const int tid = threadIdx.x;
  const int lane = tid & 63;
  const int w = tid >> 6;             // 0..7
  const int lr = lane & 15, lg = lane >> 4;
  const int wr = w >> 2, wc = w & 3;  // wave owns C rows wr*128..+128, cols wc*64..+64

  const int wg = blockIdx.x;          // 0..479
  const int xcd = wg & 7, idx = wg >> 3;  // idx 0..59
  const int bx = xcd * 4 + (idx & 3);
  const int by = idx >> 2;
  const int r0 = bx * 256, c0 = by * 256;
  const char* asrc = (const char*)(A + (size_t)r0 * KDIM);
  const char* bsrc = (const char*)(Bw + (size_t)c0 * KDIM);

  f32x4 acc[8][4] = {};

  auto stage = [&](int buf, int kt) {
    const size_t kb = (size_t)kt * 128;  // byte offset into K dim
#pragma unroll
    for (int i = 0; i < 8; ++i) {
      const int L = i * 8192 + tid * 16;       // 0..65535 linear dest
      const int r = (L & 32767) >> 7;          // row within A or B panel
      const int coff = (L & 127) ^ ((r & 7) << 4);  // inverse-swizzled source
      const char* s = (i < 4 ? asrc : bsrc) + (size_t)r * 2560 + kb + coff;
      gload16(s, &smem[buf][L]);
    }
  };

  auto compute = [&](int buf) {
#pragma unroll
    for (int kk = 0; kk < 2; ++kk) {
      bf16x8 af[8], bfr[4];
#pragma unroll
      for (int rt = 0; rt < 8; ++rt) {
        const int row = wr * 128 + rt * 16 + lr;
        af[rt] = *reinterpret_cast<const bf16x8*>(
            &smem[buf][row * 128 + ((kk * 64 + lg * 16) ^ ((row & 7) << 4))]);
      }
#pragma unroll
      for (int ct = 0; ct < 4; ++ct) {
        const int row = wc * 64 + ct * 16 + lr;
        bfr[ct] = *reinterpret_cast<const bf16x8*>(
            &smem[buf][32768 + row * 128 + ((kk * 64 + lg * 16) ^ ((row & 7) << 4))]);
      }
#pragma unroll
      for (int rt = 0; rt < 8; ++rt)
#pragma unroll
        for (int ct = 0; ct < 4; ++ct)
          acc[rt][ct] = mfma_bf16(af[rt], bfr[ct], acc[rt][ct]);
    }
  };

  stage(0, 0);
  asm volatile("s_waitcnt vmcnt(0)" ::: "memory");
  __builtin_amdgcn_s_barrier();
  __builtin_amdgcn_sched_barrier(0);

  for (int t = 0; t < 20; ++t) {
    const int buf = t & 1;
    if (t < 19) stage(buf ^ 1, t + 1);  // writes slot holding K-tile t-1 (readers done)
    compute(buf);
    __builtin_amdgcn_sched_barrier(0);
    asm volatile("s_waitcnt vmcnt(0)" ::: "memory");  // t+1 landed (issued ~1 phase ago)
    __builtin_amdgcn_sched_barrier(0);
    __builtin_amdgcn_s_barrier();
    __builtin_amdgcn_sched_barrier(0);
  }

  const int which = c0 / DMODEL;  // block-uniform (1280 = 5 x 256)
  float biasr[4];
#pragma unroll
  for (int ct = 0; ct < 4; ++ct) biasr[ct] = bias[c0 + wc * 64 + ct * 16 + lr];

#pragma unroll
  for (int ct = 0; ct < 4; ++ct) {
    const int c = c0 + wc * 64 + ct * 16 + lr;
    const int ee = c - which * DMODEL;
    const int h = ee / DHEAD;
    const int dh = ee - h * DHEAD;
#pragma unroll
    for (int rt = 0; rt < 8; ++rt)
#pragma unroll
      for (int j = 0; j < 4; ++j) {
        const int r = r0 + wr * 128 + rt * 16 + lg * 4 + j;
        const int s = r >> 2, b = r & 3;
        const __bf16 bv = (__bf16)(acc[rt][ct][j] + biasr[ct]);
        if (which == 0)
          qw[((size_t)(b * NHEAD + h) * S_LEN + s) * DHEAD + dh] = bv;
        else if (which == 1)
          kw[((size_t)(b * NHEAD + h) * S_LEN + s) * DHEAD + dh] = bv;
        else {
          const int sp = (s & ~31) | ((s & 12) << 1) | ((s & 16) >> 2) | (s & 3);
          vtw[((size_t)(b * NHEAD + h) * DHEAD + dh) * S_LEN + sp] = bv;
        }
      }
  }
}

// ---------------- out-proj GEMM (128x128, unchanged from R6) ----------------
template <int MODE>
__global__ __launch_bounds__(256) void gemm_bt(
    const __bf16* __restrict__ A, const __bf16* __restrict__ Bw,
    const float* __restrict__ bias, float* __restrict__ outf)
{
  __shared__ __align__(16) char smem[2][2][16384];
  const int tid = threadIdx.x;
  const int lane = tid & 63;
  const int w = tid >> 6;
  const int lr = lane & 15, lg = lane >> 4;
  const int rowblk = (w >> 1) * 64, colblk = (w & 1) * 64;
  const int sxz = (lane & 7) << 4;

  const int wg = blockIdx.x;
  const int xcd = wg & 7, idx = wg >> 3;
  const int bx = xcd * 8 + (idx & 7);
  const int by = idx >> 3;
  const int r0 = bx * 128;
  const int c0 = by * 128;
  const char* asrc = (const char*)(A + (size_t)r0 * KDIM);
  const char* bsrc = (const char*)(Bw + (size_t)c0 * KDIM);

  f32x4 acc[4][4] = {};

  auto stage = [&](int buf, int kt) {
    const size_t kb = (size_t)kt * 128;
#pragma unroll
    for (int i = 0; i < 4; ++i) {
      int L = i * 4096 + tid * 16;
      int r = L >> 7;
      int coff = (L & 127) ^ ((r & 7) << 4);
      gload16(asrc + (size_t)r * 2560 + kb + coff, &smem[buf][0][L]);
      gload16(bsrc + (size_t)r * 2560 + kb + coff, &smem[buf][1][L]);
    }
  };

  auto compute = [&](int buf) {
#pragma unroll
    for (int kk = 0; kk < 2; ++kk) {
      const int cb = (kk * 64 + lg * 16) ^ sxz;
      bf16x8 af[4], bfr[4];
#pragma unroll
      for (int rf = 0; rf < 4; ++rf)
        af[rf] = *reinterpret_cast<const bf16x8*>(&smem[buf][0][(rowblk + rf * 16 + lr) * 128 + cb]);
#pragma unroll
      for (int cf = 0; cf < 4; ++cf)
        bfr[cf] = *reinterpret_cast<const bf16x8*>(&smem[buf][1][(colblk + cf * 16 + lr) * 128 + cb]);
#pragma unroll
      for (int rf = 0; rf < 4; ++rf)
#pragma unroll
        for (int cf = 0; cf < 4; ++cf)
          acc[rf][cf] = mfma_bf16(af[rf], bfr[cf], acc[rf][cf]);
    }
  };

  stage(0, 0);
  asm volatile("s_waitcnt vmcnt(0)" ::: "memory");
  __builtin_amdgcn_s_barrier();
  __builtin_amdgcn_sched_barrier(0);

  for (int t = 0; t < 20; ++t) {
    const int buf = t & 1;
    if (t < 19) {
      stage(buf ^ 1, t + 1);
      asm volatile("s_waitcnt vmcnt(8)" ::: "memory");
    } else {
      asm volatile("s_waitcnt vmcnt(0)" ::: "memory");
    }
    __builtin_amdgcn_sched_barrier(0);
    __builtin_amdgcn_s_barrier();
    __builtin_amdgcn_sched_barrier(0);

    compute(buf);

    __builtin_amdgcn_sched_barrier(0);
    __builtin_amdgcn_s_barrier();
    __builtin_amdgcn_sched_barrier(0);
  }

  float biasr[4];
#pragma unroll
  for (int cf = 0; cf < 4; ++cf) biasr[cf] = bias[c0 + colblk + cf * 16 + lr];

#pragma unroll
  for (int rf = 0; rf < 4; ++rf)
#pragma unroll
    for (int cf = 0; cf < 4; ++cf) {
      const int c = c0 + colblk + cf * 16 + lr;
#pragma unroll
      for (int j = 0; j < 4; ++j) {
        const int r = r0 + rowblk + rf * 16 + lg * 4 + j;
        outf[(size_t)r * DMODEL + c] = acc[rf][cf][j] + biasr[cf];
      }
    }
}

// ---------------- RoPE in-place on q,k; q additionally pre-scaled by scale*log2e ----------------
__global__ void rope_kernel(__bf16* __restrict__ qw, __bf16* __restrict__ kw,
                            const float* __restrict__ ctab, const float* __restrict__ stab,
                            float qscale)
{
  int idx = blockIdx.x * 256 + threadIdx.x;  // 2*64*2048*10 threads
  const int j = idx % 10;
  int rest = idx / 10;
  const int s = rest & (S_LEN - 1);
  rest >>= 11;
  const int bh = rest & 63;
  const int isk = rest >> 6;
  __bf16* base = (isk ? kw : qw) + ((size_t)bh * S_LEN + s) * DHEAD;
  const float4 c4 = *reinterpret_cast<const float4*>(ctab + s * 40 + j * 4);
  const float4 s4 = *reinterpret_cast<const float4*>(stab + s * 40 + j * 4);
  bf16x4 a = *reinterpret_cast<bf16x4*>(base + j * 4);
  bf16x4 b = *reinterpret_cast<bf16x4*>(base + 40 + j * 4);
  const float m = isk ? 1.0f : qscale;
  const float cc[4] = {c4.x, c4.y, c4.z, c4.w};
  const float ss[4] = {s4.x, s4.y, s4.z, s4.w};
#pragma unroll
  for (int t = 0; t < 4; ++t) {
    float fa = (float)a[t], fb = (float)b[t];
    a[t] = (__bf16)((fa * cc[t] - fb * ss[t]) * m);
    b[t] = (__bf16)((fb * cc[t] + fa * ss[t]) * m);
  }
  *reinterpret_cast<bf16x4*>(base + j * 4) = a;
  *reinterpret_cast<bf16x4*>(base + 40 + j * 4) = b;
}

// ---------------- attention v5 = v3 + VALU cuts ----------------
// (a) __builtin_amdgcn_exp2f (single v_exp_f32, compiler-managed TRANS hazard)
// (b) hoisted staging pointers advancing by constant stride
// (c) den via constant-ones MFMA (exact row-sum of P on the matrix pipe)
__global__ __launch_bounds__(256, 3) void attn_kernel(
    const __bf16* __restrict__ qw, const __bf16* __restrict__ kw,
    const __bf16* __restrict__ vtw, __bf16* __restrict__ ow,
    const float* __restrict__ zp)
{
  __shared__ __align__(1024) char smem[2][24576];  // [buf][K 12KB | V 12KB]

  const int tid = threadIdx.x;
  const int lane = tid & 63;
  const int w = tid >> 6;             // 0..3
  const int lr = lane & 15, lg = lane >> 4;

  // XCD-aware mapping: all 16 q-tiles of one bh on one XCD
  const int wg = blockIdx.x;          // 0..1023
  const int local = wg >> 3;
  const int bh = (wg & 7) * 8 + (local >> 4);
  const int qt = local & 15;

  const char* qbase = (const char*)(qw + ((size_t)bh * S_LEN + qt * 128) * DHEAD);
  const char* kbase = (const char*)(kw + (size_t)bh * S_LEN * DHEAD);
  const char* vbase = (const char*)(vtw + (size_t)bh * DHEAD * S_LEN);
  const char* zpb = (const char*)zp;

  bf16x8 z8, one8;
#pragma unroll
  for (int i = 0; i < 8; ++i) { z8[i] = (__bf16)0.0f; one8[i] = (__bf16)1.0f; }

  // Q fragments (B-operand): q = w*32 + m*16 + lr, d-chunks {0..31,32..63,64..79+pad}
  bf16x8 aq[2][3];
#pragma unroll
  for (int m = 0; m < 2; ++m) {
    const char* rp = qbase + (size_t)(w * 32 + m * 16 + lr) * 160;
    aq[m][0] = *reinterpret_cast<const bf16x8*>(rp + lg * 16);
    aq[m][1] = *reinterpret_cast<const bf16x8*>(rp + 64 + lg * 16);
    aq[m][2] = (lg < 2) ? *reinterpret_cast<const bf16x8*>(rp + 128 + lg * 16) : z8;
  }

  // Hoisted staging sources: wave w owns slots w*6..w*6+5 of 24 x 1KB slots.
  // K slots s=ks*4+n (0..11), V slots 12..23 (mf*2+ks2, mf=5 -> zeropage trash).
  // Advance by constant stride per kv-64 tile; every wave issues exactly 6 loads.
  const char* src[6];
  size_t step[6];
#pragma unroll
  for (int i = 0; i < 6; ++i) {
    const int s = w * 6 + i;
    if (s < 12) {
      const int ks = s >> 2, n = s & 3;
      if (ks == 2 && lg >= 2) { src[i] = zpb + lane * 16; step[i] = 0; }
      else { src[i] = kbase + (size_t)(n * 16 + lr) * 160 + ks * 64 + lg * 16; step[i] = 64 * 160; }
    } else {
      const int v = s - 12, mf = v >> 1, ks2 = v & 1;
      if (mf == 5) { src[i] = zpb + lane * 16; step[i] = 0; }
      else { src[i] = vbase + (size_t)(mf * 16 + lr) * 4096 + (size_t)(ks2 * 32 + lg * 8) * 2; step[i] = 128; }
    }
  }

  auto stage = [&](int buf) {
#pragma unroll
    for (int i = 0; i < 6; ++i) {
      gload16(src[i], &smem[buf][(w * 6 + i) * 1024]);
      src[i] += step[i];
    }
  };

  f32x4 accO[5][2] = {};  // O[dh = mf*16+lg*4+j][q = w*32 + m*16 + lr]
  f32x4 accD[2] = {};     // den(q=lr) in every lane/reg via ones-MFMA

  stage(0);
  asm volatile("s_waitcnt vmcnt(0)" ::: "memory");
  __builtin_amdgcn_s_barrier();
  __builtin_amdgcn_sched_barrier(0);

  for (int t = 0; t < 32; ++t) {
    const int buf = t & 1;
    if (t < 31) {
      stage(buf ^ 1);                                  // prefetch stays in flight
      asm volatile("s_waitcnt vmcnt(6)" ::: "memory"); // tile t landed; t+1 flying
    } else {
      asm volatile("s_waitcnt vmcnt(0)" ::: "memory");
    }
    __builtin_amdgcn_sched_barrier(0);
    __builtin_amdgcn_s_barrier();   // tile t visible to all waves
    __builtin_amdgcn_sched_barrier(0);

    const char* Kb = smem[buf];
    const char* Vb = smem[buf] + 12288;

    // S^T = K * Q^T  (Q pre-scaled by scale*log2e, so p = exp2(s))
    f32x4 sc[2][4] = {};
#pragma unroll
    for (int n = 0; n < 4; ++n) {
      bf16x8 af0 = *reinterpret_cast<const bf16x8*>(Kb + (0 * 4 + n) * 1024 + lane * 16);
      bf16x8 af1 = *reinterpret_cast<const bf16x8*>(Kb + (1 * 4 + n) * 1024 + lane * 16);
      bf16x8 af2 = *reinterpret_cast<const bf16x8*>(Kb + (2 * 4 + n) * 1024 + lane * 16);
#pragma unroll
      for (int m = 0; m < 2; ++m) {
        sc[m][n] = mfma_bf16(af0, aq[m][0], sc[m][n]);
        sc[m][n] = mfma_bf16(af1, aq[m][1], sc[m][n]);
        sc[m][n] = mfma_bf16(af2, aq[m][2], sc[m][n]);
      }
    }

    // p = exp2(s); lane-local P pack (permuted k-order)
    bf16x8 bp[2][2];
#pragma unroll
    for (int m = 0; m < 2; ++m)
#pragma unroll
      for (int n = 0; n < 4; ++n) {
#pragma unroll
        for (int j = 0; j < 4; ++j)
          bp[m][n >> 1][(n & 1) * 4 + j] = (__bf16)__builtin_amdgcn_exp2f(sc[m][n][j]);
      }

    // O += P*V (V pre-permuted in global); den += ones*P on the MFMA pipe
#pragma unroll
    for (int ks2 = 0; ks2 < 2; ++ks2) {
#pragma unroll
      for (int mf = 0; mf < 5; ++mf) {
        bf16x8 av = *reinterpret_cast<const bf16x8*>(Vb + (mf * 2 + ks2) * 1024 + lane * 16);
        accO[mf][0] = mfma_bf16(av, bp[0][ks2], accO[mf][0]);
        accO[mf][1] = mfma_bf16(av, bp[1][ks2], accO[mf][1]);
      }
      accD[0] = mfma_bf16(one8, bp[0][ks2], accD[0]);
      accD[1] = mfma_bf16(one8, bp[1][ks2], accD[1]);
    }

    __builtin_amdgcn_sched_barrier(0);
    __builtin_amdgcn_s_barrier();   // reads done -> next iter may overwrite buf^1
    __builtin_amdgcn_sched_barrier(0);
  }

  __syncthreads();

  // every lane already holds den(q = w*32 + m*16 + lr) in accD[m][0]
  float rinv[2];
#pragma unroll
  for (int m = 0; m < 2; ++m) rinv[m] = 1.0f / accD[m][0];

  // O -> LDS (reuse smem), then coalesced global write
  char* sOut = smem[0];
#pragma unroll
  for (int mf = 0; mf < 5; ++mf)
#pragma unroll
    for (int m = 0; m < 2; ++m) {
      bf16x4 o4;
#pragma unroll
      for (int j = 0; j < 4; ++j) o4[j] = (__bf16)(accO[mf][m][j] * rinv[m]);
      *reinterpret_cast<bf16x4*>(sOut + (size_t)(w * 32 + m * 16 + lr) * 160 + (mf * 16 + lg * 4) * 2) = o4;
    }
  __syncthreads();

  const int b = bh >> 4, h = bh & 15;
#pragma unroll
  for (int i = 0; i < 5; ++i) {
    int c = i * 256 + tid;
    int row = c / 10, slot = c - row * 10;
    int token = (qt * 128 + row) * 4 + b;
    *reinterpret_cast<bf16x8*>((char*)ow + (size_t)token * 2560 + h * 160 + slot * 16) =
        *reinterpret_cast<const bf16x8*>(sOut + row * 160 + slot * 16);
  }
}

// ---------------- launcher ----------------
extern "C" void kernel_launch(void* const* d_in, const int* in_sizes, int n_in,
                              void* d_out, int out_size, void* d_ws, size_t ws_size,
                              hipStream_t stream)
{
  const float* hidden = (const float*)d_in[0];
  const float* rot    = (const float*)d_in[1];
  const float* w1     = (const float*)d_in[2];
  const float* b1     = (const float*)d_in[3];
  const float* w2     = (const float*)d_in[4];
  const float* b2     = (const float*)d_in[5];
  float* out = (float*)d_out;

  char* ws = (char*)d_ws;
  __bf16* Xbf  = (__bf16*)(ws);                 // 8192x1280 bf16      = 20,971,520 B
  __bf16* W1bf = (__bf16*)(ws + 20971520);      // 3840x1280 bf16      =  9,830,400 B
  __bf16* W2bf = (__bf16*)(ws + 30801920);      // 1280x1280 bf16      =  3,276,800 B
  float*  ctab = (float*)(ws + 34078720);       // 2048x40 f32         =    327,680 B
  float*  stab = (float*)(ws + 34406400);       //                     =    327,680 B
  __bf16* qwp  = (__bf16*)(ws + 34734080);      // [B,H,S,80] bf16     = 20,971,520 B
  __bf16* kwp  = (__bf16*)(ws + 55705600);      // [B,H,S,80] bf16     = 20,971,520 B
  __bf16* vtwp = (__bf16*)(ws + 76677120);      // [B,H,80,S] bf16 (sigma-permuted) = 20,971,520 B
  __bf16* owp  = (__bf16*)(ws + 97648640);      // [S*B,1280] bf16     = 20,971,520 B
  float*  zp   = (float*)(ws + 118620160);      // 4KB zero page

  cast_f32_to_bf16<<<10240, 256, 0, stream>>>(hidden, Xbf, 2621440);
  cast_f32_to_bf16<<<4800, 256, 0, stream>>>(w1, W1bf, 1228800);
  cast_f32_to_bf16<<<1600, 256, 0, stream>>>(w2, W2bf, 409600);
  build_sincos<<<320, 256, 0, stream>>>(rot, ctab, stab, 81920);
  zero_fill<<<4, 256, 0, stream>>>(zp, 1024);

  gemm256_qkv<<<480, 512, 0, stream>>>(Xbf, W1bf, b1, qwp, kwp, vtwp);

  const float qscale = 1.4426950408889634f / sqrtf(80.0f);  // scale * log2(e), folded into Q
  rope_kernel<<<10240, 256, 0, stream>>>(qwp, kwp, ctab, stab, qscale);

  attn_kernel<<<1024, 256, 0, stream>>>(qwp, kwp, vtwp, owp, zp);

  gemm_bt<1><<<640, 256, 0, stream>>>(owp, W2bf, b2, out);
}

// Round 8
// 271.970 us; speedup vs baseline: 1.1842x; 1.0160x over previous
//
#include <hip/hip_runtime.h>
#include <hip/hip_bf16.h>
#include <math.h>

typedef __bf16 bf16x4 __attribute__((ext_vector_type(4)));
typedef __bf16 bf16x8 __attribute__((ext_vector_type(8)));
typedef float  f32x4  __attribute__((ext_vector_type(4)));

#define S_LEN 2048
#define BATCH 4
#define DMODEL 1280
#define NHEAD 16
#define DHEAD 80
#define KDIM 1280

__device__ __forceinline__ f32x4 mfma_bf16(bf16x8 a, bf16x8 b, f32x4 c) {
  return __builtin_amdgcn_mfma_f32_16x16x32_bf16(a, b, c, 0, 0, 0);
}

__device__ __forceinline__ void gload16(const void* g, void* l) {
  __builtin_amdgcn_global_load_lds(
      (const __attribute__((address_space(1))) unsigned int*)g,
      (__attribute__((address_space(3))) unsigned int*)l, 16, 0, 0);
}

// ---------------- fp32 -> bf16 cast (vectorized) ----------------
__global__ void cast_f32_to_bf16(const float* __restrict__ in,
                                 __bf16* __restrict__ out, int n4) {
  int i = blockIdx.x * 256 + threadIdx.x;
  if (i >= n4) return;
  float4 v = reinterpret_cast<const float4*>(in)[i];
  bf16x4 o;
  o[0] = (__bf16)v.x; o[1] = (__bf16)v.y; o[2] = (__bf16)v.z; o[3] = (__bf16)v.w;
  reinterpret_cast<bf16x4*>(out)[i] = o;
}

// ---------------- sin/cos tables [S][40] ----------------
__global__ void build_sincos(const float* __restrict__ rot,
                             float* __restrict__ ctab, float* __restrict__ stab, int n) {
  int i = blockIdx.x * 256 + threadIdx.x;
  if (i >= n) return;
  float v = rot[i];
  ctab[i] = cosf(v);
  stab[i] = sinf(v);
}

// ---------------- zero page ----------------
__global__ void zero_fill(float* __restrict__ p, int n) {
  int i = blockIdx.x * 256 + threadIdx.x;
  if (i < n) p[i] = 0.0f;
}

// ---------------- QKV GEMM, 256x256 tile, BK=64, 8 waves, phase-interleaved ----------------
// 4 phases/K-tile, 16 MFMA each, counted vmcnt(2) at two sync points/tile.
// Wave (wr,wc) reads only A-half(wr) + B-quarter(wc); staging is reassigned so each
// wave stages exactly its own operands (4 A-loads + 4 B-loads per thread per tile),
// making wave-local vmcnt + barrier a complete landing proof.
// Ledger (per wave, steady state):
//   t.P1: issue B0',B1'(t+1). outstanding = {A2,A3(t), B0',B1'} = 4.
//         after MFMA: vmcnt(2) -> A2,A3(t) done; barrier -> A-halves(t) complete -> P2 safe.
//   t.P2: issue B2',B3'. t.P3: issue A0',A1'. t.P4: issue A2',A3'. outstanding = 8.
//         vmcnt(2) -> B'(all)+A0',A1' done; barrier -> t+1.P1 operands complete.
__global__ __launch_bounds__(512, 2) void gemm256_qkv(
    const __bf16* __restrict__ A, const __bf16* __restrict__ Bw,
    const float* __restrict__ bias,
    __bf16* __restrict__ qw, __bf16* __restrict__ kw, __bf16* __restrict__ vtw)
{
  __shared__ __align__(1024) char smem[2][65536];  // [slot][A 32KB | B 32KB]
  const int tid = threadIdx.x;
  const int lane = tid & 63;
  const int w = tid >> 6;             // 0..7
  const int lr = lane & 15, lg = lane >> 4;
  const int wr = w >> 2, wc = w & 3;  // wave owns C rows wr*128..+128, cols wc*64..+64

  const int wg = blockIdx.x;          // 0..479
  const int xcd = wg & 7, idx = wg >> 3;  // idx 0..59
  const int bx = xcd * 4 + (idx & 3);
  const int by = idx >> 2;
  const int r0 = bx * 256, c0 = by * 256;
  const char* asrc = (const char*)(A + (size_t)r0 * KDIM);
  const char* bsrc = (const char*)(Bw + (size_t)c0 * KDIM);

  f32x4 acc[8][4] = {};

  // per-thread staging slots: [0..3] = B-quarter(wc), [4..7] = A-half(wr).
  // dest fixed; source advances 128 B per K-tile. Last tile stages a dummy
  // 21st tile whose source spills 128 B into the adjacent ws buffer (safe, unused).
  const char* gsrc[8];
  int gdst[8];
#pragma unroll
  for (int i = 0; i < 4; ++i) {  // B-quarter(wc): 8 KB, staged by its 2 reader waves
    const int d = 32768 + wc * 8192 + i * 2048 + wr * 1024 + lane * 16;
    const int r = (d - 32768) >> 7;
    const int coff = (d & 127) ^ ((r & 7) << 4);
    gdst[i] = d;
    gsrc[i] = bsrc + (size_t)r * 2560 + coff;
  }
#pragma unroll
  for (int i = 0; i < 4; ++i) {  // A-half(wr): 16 KB, staged by its 4 reader waves
    const int d = wr * 16384 + i * 4096 + wc * 1024 + lane * 16;
    const int r = d >> 7;
    const int coff = (d & 127) ^ ((r & 7) << 4);
    gdst[4 + i] = d;
    gsrc[4 + i] = asrc + (size_t)r * 2560 + coff;
  }

  auto issue = [&](int buf, int i) {
    gload16(gsrc[i], &smem[buf][gdst[i]]);
    gsrc[i] += 128;
  };

  auto ldA = [&](bf16x8* af, const char* Ab, int rtbase, int kk) {
#pragma unroll
    for (int i = 0; i < 4; ++i) {
      const int row = wr * 128 + (rtbase + i) * 16 + lr;
      af[i] = *reinterpret_cast<const bf16x8*>(
          &Ab[row * 128 + ((kk * 64 + lg * 16) ^ ((row & 7) << 4))]);
    }
  };
  auto ldB = [&](bf16x8* bfr, const char* Bb, int kk) {
#pragma unroll
    for (int ct = 0; ct < 4; ++ct) {
      const int row = wc * 64 + ct * 16 + lr;
      bfr[ct] = *reinterpret_cast<const bf16x8*>(
          &Bb[row * 128 + ((kk * 64 + lg * 16) ^ ((row & 7) << 4))]);
    }
  };

  // prologue: stage tile 0 fully, drain, barrier
#pragma unroll
  for (int i = 0; i < 8; ++i) issue(0, i);
  asm volatile("s_waitcnt vmcnt(0)" ::: "memory");
  __builtin_amdgcn_s_barrier();
  __builtin_amdgcn_sched_barrier(0);

  for (int t = 0; t < 20; ++t) {
    const int cbuf = t & 1, nbuf = cbuf ^ 1;
    const char* Ab = smem[cbuf];
    const char* Bb = smem[cbuf] + 32768;
    bf16x8 af[4], bfr[4];

    // ---- P1: kk0, rt0-3 ----
    ldA(af, Ab, 0, 0);
    ldB(bfr, Bb, 0);
    issue(nbuf, 0); issue(nbuf, 1);
    __builtin_amdgcn_s_setprio(1);
#pragma unroll
    for (int i = 0; i < 4; ++i)
#pragma unroll
      for (int ct = 0; ct < 4; ++ct)
        acc[i][ct] = mfma_bf16(af[i], bfr[ct], acc[i][ct]);
    __builtin_amdgcn_s_setprio(0);
    __builtin_amdgcn_sched_barrier(0);
    asm volatile("s_waitcnt vmcnt(2)" ::: "memory");  // A2,A3 of tile t landed
    __builtin_amdgcn_sched_barrier(0);
    __builtin_amdgcn_s_barrier();                     // -> A-halves(t) complete
    __builtin_amdgcn_sched_barrier(0);

    // ---- P2: kk0, rt4-7 (bfr reused) ----
    ldA(af, Ab, 4, 0);
    issue(nbuf, 2); issue(nbuf, 3);
    __builtin_amdgcn_s_setprio(1);
#pragma unroll
    for (int i = 0; i < 4; ++i)
#pragma unroll
      for (int ct = 0; ct < 4; ++ct)
        acc[4 + i][ct] = mfma_bf16(af[i], bfr[ct], acc[4 + i][ct]);
    __builtin_amdgcn_s_setprio(0);

    // ---- P3: kk1, rt0-3 ----
    ldA(af, Ab, 0, 1);
    ldB(bfr, Bb, 1);
    issue(nbuf, 4); issue(nbuf, 5);
    __builtin_amdgcn_s_setprio(1);
#pragma unroll
    for (int i = 0; i < 4; ++i)
#pragma unroll
      for (int ct = 0; ct < 4; ++ct)
        acc[i][ct] = mfma_bf16(af[i], bfr[ct], acc[i][ct]);
    __builtin_amdgcn_s_setprio(0);

    // ---- P4: kk1, rt4-7 ----
    ldA(af, Ab, 4, 1);
    issue(nbuf, 6); issue(nbuf, 7);
    __builtin_amdgcn_s_setprio(1);
#pragma unroll
    for (int i = 0; i < 4; ++i)
#pragma unroll
      for (int ct = 0; ct < 4; ++ct)
        acc[4 + i][ct] = mfma_bf16(af[i], bfr[ct], acc[4 + i][ct]);
    __builtin_amdgcn_s_setprio(0);
    __builtin_amdgcn_sched_barrier(0);
    asm volatile("s_waitcnt vmcnt(2)" ::: "memory");  // B(all)+A0,A1 of t+1 landed
    __builtin_amdgcn_sched_barrier(0);
    __builtin_amdgcn_s_barrier();                     // -> t+1.P1 operands complete
    __builtin_amdgcn_sched_barrier(0);
  }

  // epilogue: scatter (unchanged)
  const int which = c0 / DMODEL;  // block-uniform (1280 = 5 x 256)
  float biasr[4];
#pragma unroll
  for (int ct = 0; ct < 4; ++ct) biasr[ct] = bias[c0 + wc * 64 + ct * 16 + lr];

#pragma unroll
  for (int ct = 0; ct < 4; ++ct) {
    const int c = c0 + wc * 64 + ct * 16 + lr;
    const int ee = c - which * DMODEL;
    const int h = ee / DHEAD;
    const int dh = ee - h * DHEAD;
#pragma unroll
    for (int rt = 0; rt < 8; ++rt)
#pragma unroll
      for (int j = 0; j < 4; ++j) {
        const int r = r0 + wr * 128 + rt * 16 + lg * 4 + j;
        const int s = r >> 2, b = r & 3;
        const __bf16 bv = (__bf16)(acc[rt][ct][j] + biasr[ct]);
        if (which == 0)
          qw[((size_t)(b * NHEAD + h) * S_LEN + s) * DHEAD + dh] = bv;
        else if (which == 1)
          kw[((size_t)(b * NHEAD + h) * S_LEN + s) * DHEAD + dh] = bv;
        else {
          const int sp = (s & ~31) | ((s & 12) << 1) | ((s & 16) >> 2) | (s & 3);
          vtw[((size_t)(b * NHEAD + h) * DHEAD + dh) * S_LEN + sp] = bv;
        }
      }
  }
}

// ---------------- out-proj GEMM (128x128, unchanged from R6) ----------------
template <int MODE>
__global__ __launch_bounds__(256) void gemm_bt(
    const __bf16* __restrict__ A, const __bf16* __restrict__ Bw,
    const float* __restrict__ bias, float* __restrict__ outf)
{
  __shared__ __align__(16) char smem[2][2][16384];
  const int tid = threadIdx.x;
  const int lane = tid & 63;
  const int w = tid >> 6;
  const int lr = lane & 15, lg = lane >> 4;
  const int rowblk = (w >> 1) * 64, colblk = (w & 1) * 64;
  const int sxz = (lane & 7) << 4;

  const int wg = blockIdx.x;
  const int xcd = wg & 7, idx = wg >> 3;
  const int bx = xcd * 8 + (idx & 7);
  const int by = idx >> 3;
  const int r0 = bx * 128;
  const int c0 = by * 128;
  const char* asrc = (const char*)(A + (size_t)r0 * KDIM);
  const char* bsrc = (const char*)(Bw + (size_t)c0 * KDIM);

  f32x4 acc[4][4] = {};

  auto stage = [&](int buf, int kt) {
    const size_t kb = (size_t)kt * 128;
#pragma unroll
    for (int i = 0; i < 4; ++i) {
      int L = i * 4096 + tid * 16;
      int r = L >> 7;
      int coff = (L & 127) ^ ((r & 7) << 4);
      gload16(asrc + (size_t)r * 2560 + kb + coff, &smem[buf][0][L]);
      gload16(bsrc + (size_t)r * 2560 + kb + coff, &smem[buf][1][L]);
    }
  };

  auto compute = [&](int buf) {
#pragma unroll
    for (int kk = 0; kk < 2; ++kk) {
      const int cb = (kk * 64 + lg * 16) ^ sxz;
      bf16x8 af[4], bfr[4];
#pragma unroll
      for (int rf = 0; rf < 4; ++rf)
        af[rf] = *reinterpret_cast<const bf16x8*>(&smem[buf][0][(rowblk + rf * 16 + lr) * 128 + cb]);
#pragma unroll
      for (int cf = 0; cf < 4; ++cf)
        bfr[cf] = *reinterpret_cast<const bf16x8*>(&smem[buf][1][(colblk + cf * 16 + lr) * 128 + cb]);
#pragma unroll
      for (int rf = 0; rf < 4; ++rf)
#pragma unroll
        for (int cf = 0; cf < 4; ++cf)
          acc[rf][cf] = mfma_bf16(af[rf], bfr[cf], acc[rf][cf]);
    }
  };

  stage(0, 0);
  asm volatile("s_waitcnt vmcnt(0)" ::: "memory");
  __builtin_amdgcn_s_barrier();
  __builtin_amdgcn_sched_barrier(0);

  for (int t = 0; t < 20; ++t) {
    const int buf = t & 1;
    if (t < 19) {
      stage(buf ^ 1, t + 1);
      asm volatile("s_waitcnt vmcnt(8)" ::: "memory");
    } else {
      asm volatile("s_waitcnt vmcnt(0)" ::: "memory");
    }
    __builtin_amdgcn_sched_barrier(0);
    __builtin_amdgcn_s_barrier();
    __builtin_amdgcn_sched_barrier(0);

    compute(buf);

    __builtin_amdgcn_sched_barrier(0);
    __builtin_amdgcn_s_barrier();
    __builtin_amdgcn_sched_barrier(0);
  }

  float biasr[4];
#pragma unroll
  for (int cf = 0; cf < 4; ++cf) biasr[cf] = bias[c0 + colblk + cf * 16 + lr];

#pragma unroll
  for (int rf = 0; rf < 4; ++rf)
#pragma unroll
    for (int cf = 0; cf < 4; ++cf) {
      const int c = c0 + colblk + cf * 16 + lr;
#pragma unroll
      for (int j = 0; j < 4; ++j) {
        const int r = r0 + rowblk + rf * 16 + lg * 4 + j;
        outf[(size_t)r * DMODEL + c] = acc[rf][cf][j] + biasr[cf];
      }
    }
}

// ---------------- RoPE in-place on q,k; q additionally pre-scaled by scale*log2e ----------------
__global__ void rope_kernel(__bf16* __restrict__ qw, __bf16* __restrict__ kw,
                            const float* __restrict__ ctab, const float* __restrict__ stab,
                            float qscale)
{
  int idx = blockIdx.x * 256 + threadIdx.x;  // 2*64*2048*10 threads
  const int j = idx % 10;
  int rest = idx / 10;
  const int s = rest & (S_LEN - 1);
  rest >>= 11;
  const int bh = rest & 63;
  const int isk = rest >> 6;
  __bf16* base = (isk ? kw : qw) + ((size_t)bh * S_LEN + s) * DHEAD;
  const float4 c4 = *reinterpret_cast<const float4*>(ctab + s * 40 + j * 4);
  const float4 s4 = *reinterpret_cast<const float4*>(stab + s * 40 + j * 4);
  bf16x4 a = *reinterpret_cast<bf16x4*>(base + j * 4);
  bf16x4 b = *reinterpret_cast<bf16x4*>(base + 40 + j * 4);
  const float m = isk ? 1.0f : qscale;
  const float cc[4] = {c4.x, c4.y, c4.z, c4.w};
  const float ss[4] = {s4.x, s4.y, s4.z, s4.w};
#pragma unroll
  for (int t = 0; t < 4; ++t) {
    float fa = (float)a[t], fb = (float)b[t];
    a[t] = (__bf16)((fa * cc[t] - fb * ss[t]) * m);
    b[t] = (__bf16)((fb * cc[t] + fa * ss[t]) * m);
  }
  *reinterpret_cast<bf16x4*>(base + j * 4) = a;
  *reinterpret_cast<bf16x4*>(base + 40 + j * 4) = b;
}

// ---------------- attention v5 (unchanged from R7) ----------------
__global__ __launch_bounds__(256, 3) void attn_kernel(
    const __bf16* __restrict__ qw, const __bf16* __restrict__ kw,
    const __bf16* __restrict__ vtw, __bf16* __restrict__ ow,
    const float* __restrict__ zp)
{
  __shared__ __align__(1024) char smem[2][24576];  // [buf][K 12KB | V 12KB]

  const int tid = threadIdx.x;
  const int lane = tid & 63;
  const int w = tid >> 6;             // 0..3
  const int lr = lane & 15, lg = lane >> 4;

  const int wg = blockIdx.x;          // 0..1023
  const int local = wg >> 3;
  const int bh = (wg & 7) * 8 + (local >> 4);
  const int qt = local & 15;

  const char* qbase = (const char*)(qw + ((size_t)bh * S_LEN + qt * 128) * DHEAD);
  const char* kbase = (const char*)(kw + (size_t)bh * S_LEN * DHEAD);
  const char* vbase = (const char*)(vtw + (size_t)bh * DHEAD * S_LEN);
  const char* zpb = (const char*)zp;

  bf16x8 z8, one8;
#pragma unroll
  for (int i = 0; i < 8; ++i) { z8[i] = (__bf16)0.0f; one8[i] = (__bf16)1.0f; }

  bf16x8 aq[2][3];
#pragma unroll
  for (int m = 0; m < 2; ++m) {
    const char* rp = qbase + (size_t)(w * 32 + m * 16 + lr) * 160;
    aq[m][0] = *reinterpret_cast<const bf16x8*>(rp + lg * 16);
    aq[m][1] = *reinterpret_cast<const bf16x8*>(rp + 64 + lg * 16);
    aq[m][2] = (lg < 2) ? *reinterpret_cast<const bf16x8*>(rp + 128 + lg * 16) : z8;
  }

  const char* src[6];
  size_t step[6];
#pragma unroll
  for (int i = 0; i < 6; ++i) {
    const int s = w * 6 + i;
    if (s < 12) {
      const int ks = s >> 2, n = s & 3;
      if (ks == 2 && lg >= 2) { src[i] = zpb + lane * 16; step[i] = 0; }
      else { src[i] = kbase + (size_t)(n * 16 + lr) * 160 + ks * 64 + lg * 16; step[i] = 64 * 160; }
    } else {
      const int v = s - 12, mf = v >> 1, ks2 = v & 1;
      if (mf == 5) { src[i] = zpb + lane * 16; step[i] = 0; }
      else { src[i] = vbase + (size_t)(mf * 16 + lr) * 4096 + (size_t)(ks2 * 32 + lg * 8) * 2; step[i] = 128; }
    }
  }

  auto stage = [&](int buf) {
#pragma unroll
    for (int i = 0; i < 6; ++i) {
      gload16(src[i], &smem[buf][(w * 6 + i) * 1024]);
      src[i] += step[i];
    }
  };

  f32x4 accO[5][2] = {};  // O[dh = mf*16+lg*4+j][q = w*32 + m*16 + lr]
  f32x4 accD[2] = {};     // den(q=lr) in every lane/reg via ones-MFMA

  stage(0);
  asm volatile("s_waitcnt vmcnt(0)" ::: "memory");
  __builtin_amdgcn_s_barrier();
  __builtin_amdgcn_sched_barrier(0);

  for (int t = 0; t < 32; ++t) {
    const int buf = t & 1;
    if (t < 31) {
      stage(buf ^ 1);                                  // prefetch stays in flight
      asm volatile("s_waitcnt vmcnt(6)" ::: "memory"); // tile t landed; t+1 flying
    } else {
      asm volatile("s_waitcnt vmcnt(0)" ::: "memory");
    }
    __builtin_amdgcn_sched_barrier(0);
    __builtin_amdgcn_s_barrier();   // tile t visible to all waves
    __builtin_amdgcn_sched_barrier(0);

    const char* Kb = smem[buf];
    const char* Vb = smem[buf] + 12288;

    // S^T = K * Q^T  (Q pre-scaled by scale*log2e, so p = exp2(s))
    f32x4 sc[2][4] = {};
#pragma unroll
    for (int n = 0; n < 4; ++n) {
      bf16x8 af0 = *reinterpret_cast<const bf16x8*>(Kb + (0 * 4 + n) * 1024 + lane * 16);
      bf16x8 af1 = *reinterpret_cast<const bf16x8*>(Kb + (1 * 4 + n) * 1024 + lane * 16);
      bf16x8 af2 = *reinterpret_cast<const bf16x8*>(Kb + (2 * 4 + n) * 1024 + lane * 16);
#pragma unroll
      for (int m = 0; m < 2; ++m) {
        sc[m][n] = mfma_bf16(af0, aq[m][0], sc[m][n]);
        sc[m][n] = mfma_bf16(af1, aq[m][1], sc[m][n]);
        sc[m][n] = mfma_bf16(af2, aq[m][2], sc[m][n]);
      }
    }

    // p = exp2(s); lane-local P pack (permuted k-order)
    bf16x8 bp[2][2];
#pragma unroll
    for (int m = 0; m < 2; ++m)
#pragma unroll
      for (int n = 0; n < 4; ++n) {
#pragma unroll
        for (int j = 0; j < 4; ++j)
          bp[m][n >> 1][(n & 1) * 4 + j] = (__bf16)__builtin_amdgcn_exp2f(sc[m][n][j]);
      }

    // O += P*V (V pre-permuted in global); den += ones*P on the MFMA pipe
#pragma unroll
    for (int ks2 = 0; ks2 < 2; ++ks2) {
#pragma unroll
      for (int mf = 0; mf < 5; ++mf) {
        bf16x8 av = *reinterpret_cast<const bf16x8*>(Vb + (mf * 2 + ks2) * 1024 + lane * 16);
        accO[mf][0] = mfma_bf16(av, bp[0][ks2], accO[mf][0]);
        accO[mf][1] = mfma_bf16(av, bp[1][ks2], accO[mf][1]);
      }
      accD[0] = mfma_bf16(one8, bp[0][ks2], accD[0]);
      accD[1] = mfma_bf16(one8, bp[1][ks2], accD[1]);
    }

    __builtin_amdgcn_sched_barrier(0);
    __builtin_amdgcn_s_barrier();   // reads done -> next iter may overwrite buf^1
    __builtin_amdgcn_sched_barrier(0);
  }

  __syncthreads();

  float rinv[2];
#pragma unroll
  for (int m = 0; m < 2; ++m) rinv[m] = 1.0f / accD[m][0];

  char* sOut = smem[0];
#pragma unroll
  for (int mf = 0; mf < 5; ++mf)
#pragma unroll
    for (int m = 0; m < 2; ++m) {
      bf16x4 o4;
#pragma unroll
      for (int j = 0; j < 4; ++j) o4[j] = (__bf16)(accO[mf][m][j] * rinv[m]);
      *reinterpret_cast<bf16x4*>(sOut + (size_t)(w * 32 + m * 16 + lr) * 160 + (mf * 16 + lg * 4) * 2) = o4;
    }
  __syncthreads();

  const int b = bh >> 4, h = bh & 15;
#pragma unroll
  for (int i = 0; i < 5; ++i) {
    int c = i * 256 + tid;
    int row = c / 10, slot = c - row * 10;
    int token = (qt * 128 + row) * 4 + b;
    *reinterpret_cast<bf16x8*>((char*)ow + (size_t)token * 2560 + h * 160 + slot * 16) =
        *reinterpret_cast<const bf16x8*>(sOut + row * 160 + slot * 16);
  }
}

// ---------------- launcher ----------------
extern "C" void kernel_launch(void* const* d_in, const int* in_sizes, int n_in,
                              void* d_out, int out_size, void* d_ws, size_t ws_size,
                              hipStream_t stream)
{
  const float* hidden = (const float*)d_in[0];
  const float* rot    = (const float*)d_in[1];
  const float* w1     = (const float*)d_in[2];
  const float* b1     = (const float*)d_in[3];
  const float* w2     = (const float*)d_in[4];
  const float* b2     = (const float*)d_in[5];
  float* out = (float*)d_out;

  char* ws = (char*)d_ws;
  __bf16* Xbf  = (__bf16*)(ws);                 // 8192x1280 bf16      = 20,971,520 B
  __bf16* W1bf = (__bf16*)(ws + 20971520);      // 3840x1280 bf16      =  9,830,400 B
  __bf16* W2bf = (__bf16*)(ws + 30801920);      // 1280x1280 bf16      =  3,276,800 B
  float*  ctab = (float*)(ws + 34078720);       // 2048x40 f32         =    327,680 B
  float*  stab = (float*)(ws + 34406400);       //                     =    327,680 B
  __bf16* qwp  = (__bf16*)(ws + 34734080);      // [B,H,S,80] bf16     = 20,971,520 B
  __bf16* kwp  = (__bf16*)(ws + 55705600);      // [B,H,S,80] bf16     = 20,971,520 B
  __bf16* vtwp = (__bf16*)(ws + 76677120);      // [B,H,80,S] bf16 (sigma-permuted) = 20,971,520 B
  __bf16* owp  = (__bf16*)(ws + 97648640);      // [S*B,1280] bf16     = 20,971,520 B
  float*  zp   = (float*)(ws + 118620160);      // 4KB zero page

  cast_f32_to_bf16<<<10240, 256, 0, stream>>>(hidden, Xbf, 2621440);
  cast_f32_to_bf16<<<4800, 256, 0, stream>>>(w1, W1bf, 1228800);
  cast_f32_to_bf16<<<1600, 256, 0, stream>>>(w2, W2bf, 409600);
  build_sincos<<<320, 256, 0, stream>>>(rot, ctab, stab, 81920);
  zero_fill<<<4, 256, 0, stream>>>(zp, 1024);

  gemm256_qkv<<<480, 512, 0, stream>>>(Xbf, W1bf, b1, qwp, kwp, vtwp);

  const float qscale = 1.4426950408889634f / sqrtf(80.0f);  // scale * log2(e), folded into Q
  rope_kernel<<<10240, 256, 0, stream>>>(qwp, kwp, ctab, stab, qscale);

  attn_kernel<<<1024, 256, 0, stream>>>(qwp, kwp, vtwp, owp, zp);

  gemm_bt<1><<<640, 256, 0, stream>>>(owp, W2bf, b2, out);
}